// Round 12
// baseline (1672.716 us; speedup 1.0000x reference)
//
#include <hip/hip_runtime.h>

typedef unsigned short u16;
typedef unsigned int u32;
typedef __attribute__((ext_vector_type(8))) short bf16x8;
typedef __attribute__((ext_vector_type(4))) float f32x4;

#define T_STEPS 512
#define FEAT 128
#define H1 200
#define G1 800
#define G1P 832
#define XGW 800             // xg row stride (real cols only)
#define XG_T_BYTES 409600   // 256 * 800 * 2
#define XG_WG_BYTES 6400    // 4 * 800 * 2

// async global->LDS, 16B/lane; LDS dest wave-uniform base (+lane*16 in HW)
#define G2L16(g, lp) __builtin_amdgcn_global_load_lds( \
    (const __attribute__((address_space(1))) void*)(g), \
    (__attribute__((address_space(3))) void*)(lp), 16, 0, 0)

__device__ __forceinline__ u16 f2bf(float x) {
    u32 u = __float_as_uint(x);
    u = (u + 0x7fffu + ((u >> 16) & 1u)) >> 16;
    return (u16)u;
}
__device__ __forceinline__ float bfu2f(u32 u) { return __uint_as_float(u << 16); }

__device__ __forceinline__ float sig2(float x) {
    return __builtin_amdgcn_rcpf(1.f + __builtin_amdgcn_exp2f(-1.442695041f * x));
}
__device__ __forceinline__ float tanh2(float x) {
    return 1.f - 2.f * __builtin_amdgcn_rcpf(1.f + __builtin_amdgcn_exp2f(2.885390082f * x));
}

// ---------------------------------------------------------------------------
// Kernel 1: repack weights to bf16 MFMA B-fragment order + fused bias.
// whhf: 50 tiles [tile*7+kt][lane][8] raw cols; wihf: 52 tiles x 4 kt.
// (r4-verified verbatim)
// ---------------------------------------------------------------------------
__global__ void repack_k(const float* __restrict__ wih1, const float* __restrict__ whh1,
                         const float* __restrict__ bih1, const float* __restrict__ bhh1,
                         u16* __restrict__ wihf, u16* __restrict__ whhf, float* __restrict__ b1p) {
    int id = blockIdx.x * 256 + threadIdx.x;
    if (id < G1P) b1p[id] = (id < G1) ? (bih1[id] + bhh1[id]) : 0.f;
    if (id < 22400) { // 50*7*64 lane-slots for whh
        int l = id & 63, fi = id >> 6;
        int kt = fi % 7, tile = fi / 7;
        int n = tile * 16 + (l & 15);
        int kb = kt * 32 + (l >> 4) * 8;
        u16 o[8];
#pragma unroll
        for (int j = 0; j < 8; ++j) {
            int k = kb + j;
            float v = (k < H1) ? whh1[n * H1 + k] : 0.f;
            o[j] = f2bf(v);
        }
        uint4 pk;
        pk.x = (u32)o[0] | ((u32)o[1] << 16);
        pk.y = (u32)o[2] | ((u32)o[3] << 16);
        pk.z = (u32)o[4] | ((u32)o[5] << 16);
        pk.w = (u32)o[6] | ((u32)o[7] << 16);
        *(uint4*)(whhf + (size_t)id * 8) = pk;
    }
    int id2 = id - 22400;
    if (id2 >= 0 && id2 < 13312) { // 52*4*64 lane-slots for wih
        int l = id2 & 63, fi = id2 >> 6;
        int kt = fi & 3, ntg = fi >> 2;
        int n = ntg * 16 + (l & 15);
        int kb = kt * 32 + (l >> 4) * 8;
        u16 o[8];
#pragma unroll
        for (int j = 0; j < 8; ++j) {
            int k = kb + j;
            float v = (n < G1) ? wih1[n * FEAT + k] : 0.f;
            o[j] = f2bf(v);
        }
        uint4 pk;
        pk.x = (u32)o[0] | ((u32)o[1] << 16);
        pk.y = (u32)o[2] | ((u32)o[3] << 16);
        pk.z = (u32)o[4] | ((u32)o[5] << 16);
        pk.w = (u32)o[6] | ((u32)o[7] << 16);
        *(uint4*)(wihf + (size_t)id2 * 8) = pk;
    }
}

// ---------------------------------------------------------------------------
// Kernel 2: xg = X @ W_ih1^T + bias, bf16, natural layout xg[t][b][col 0..799]
// (r4-verified, store masked to 800-col stride)
// ---------------------------------------------------------------------------
__global__ __launch_bounds__(256, 1) void xg_gemm(const float* __restrict__ X,
                                                  const u16* __restrict__ wihf,
                                                  const float* __restrict__ b1p,
                                                  u16* __restrict__ xg) {
    __shared__ u16 xs[64 * 128];
    int tid = threadIdx.x, wg = blockIdx.x;
    int l = tid & 63, wv = tid >> 6;
    int arow = l & 15, khi = l >> 4;

    const float4* Xv = (const float4*)(X + (size_t)wg * 64 * 128);
#pragma unroll
    for (int i = 0; i < 8; ++i) {
        int idx = tid + i * 256;
        float4 v = Xv[idx];
        int row = idx >> 5;
        int col = (idx & 31) * 4;
        uint2 pk;
        pk.x = (u32)f2bf(v.x) | ((u32)f2bf(v.y) << 16);
        pk.y = (u32)f2bf(v.z) | ((u32)f2bf(v.w) << 16);
        int byteo = (row * 256 + col * 2) ^ ((row & 7) << 4);
        *(uint2*)((char*)xs + byteo) = pk;
    }
    __syncthreads();

    f32x4 acc[4][13];
#pragma unroll
    for (int mt = 0; mt < 4; ++mt)
#pragma unroll
        for (int nt = 0; nt < 13; ++nt) acc[mt][nt] = (f32x4){0.f, 0.f, 0.f, 0.f};

#pragma unroll
    for (int kt = 0; kt < 4; ++kt) {
        bf16x8 wfr[13];
#pragma unroll
        for (int nt = 0; nt < 13; ++nt) {
            int ntg = wv * 13 + nt;
            wfr[nt] = *(const bf16x8*)(wihf + ((size_t)(ntg * 4 + kt) * 64 + l) * 8);
        }
#pragma unroll
        for (int mt = 0; mt < 4; ++mt) {
            int row = mt * 16 + arow;
            int byteo = (row * 256 + kt * 64 + khi * 16) ^ ((row & 7) << 4);
            bf16x8 a = *(const bf16x8*)((const char*)xs + byteo);
#pragma unroll
            for (int nt = 0; nt < 13; ++nt)
                acc[mt][nt] = __builtin_amdgcn_mfma_f32_16x16x32_bf16(a, wfr[nt], acc[mt][nt], 0, 0, 0);
        }
    }

    int t = wg >> 2;
#pragma unroll
    for (int nt = 0; nt < 13; ++nt) {
        int ntg = wv * 13 + nt;
        int colg = ntg * 16 + arow;
        float bias = b1p[colg];
#pragma unroll
        for (int mt = 0; mt < 4; ++mt) {
#pragma unroll
            for (int r = 0; r < 4; ++r) {
                int bg = (wg & 3) * 64 + mt * 16 + khi * 4 + r;
                if (colg < G1)
                    xg[((size_t)t * 256 + bg) * XGW + colg] = f2bf(acc[mt][nt][r] + bias);
            }
        }
    }
}

// ---------------------------------------------------------------------------
// Kernel 3: persistent fused 2-layer LSTM. 64 WGs x 256 threads (4 waves,
// 1 WG/CU, 1 wave/SIMD -> 256 ARCH VGPRs granted per r3/r6 evidence).
// Per wave: 8 W_hh tiles targeted at arch VGPRs (224) + acc in AGPR (native);
// 18 tiles from LDS (r10-verified rotation). EW: wave = batch row, all lanes
// (r4-verified). hbuf = 4 real rows + broadcast-zero slot. 2 barriers/step.
// ---------------------------------------------------------------------------
#define LDHB(KT) (*(const bf16x8*)(hbc + (arow < 4 ? (((arow * 448 + (KT) * 64 + khi * 16)) ^ (arow << 4)) : 1792)))
#define LDSW(J, KT) (*(const bf16x8*)((const char*)wlds + (size_t)(((slot0 + (J)) * 7 + (KT)) * 1024) + l * 16))

template<int NL, bool L2O>
__device__ __forceinline__ void lstm_body(
    int tile0, int slot0, int wv, int l, int mw,
    const u16* __restrict__ xg, const u16* __restrict__ whhf,
    const float* __restrict__ w_ih2, const float* __restrict__ w_hh2,
    const float* __restrict__ b_ih2, const float* __restrict__ b_hh2,
    float* __restrict__ out, u16* hbuf, float* gbuf, u16* xgs, const u16* wlds)
{
    const int arow = l & 15, khi = l >> 4;
    const f32x4 fz = {0.f, 0.f, 0.f, 0.f};
    const char* hbc = (const char*)hbuf;

    // persistent W_hh B-fragments — plain loads, compiler-managed registers
    bf16x8 wf[8][7];
#pragma unroll
    for (int nt = 0; nt < 8; ++nt)
#pragma unroll
        for (int kt = 0; kt < 7; ++kt)
            wf[nt][kt] = *(const bf16x8*)(whhf + ((size_t)((tile0 + nt) * 7 + kt) * 64 + l) * 8);

    // layer-2 state (wave 3 only; DCE'd elsewhere) — r4-verified
    bf16x8 wf2[7];
    float wh[4][3], b2l[4], h2p[4], c2[4];
    f32x4 acc2 = fz;
    if constexpr (L2O) {
#pragma unroll
        for (int kt = 0; kt < 7; ++kt) {
            u16 o[8];
#pragma unroll
            for (int j = 0; j < 8; ++j) {
                int k = kt * 32 + khi * 8 + j;
                o[j] = (arow < 12 && k < H1) ? f2bf(w_ih2[arow * H1 + k]) : (u16)0;
            }
            uint4 pk;
            pk.x = (u32)o[0] | ((u32)o[1] << 16);
            pk.y = (u32)o[2] | ((u32)o[3] << 16);
            pk.z = (u32)o[4] | ((u32)o[5] << 16);
            pk.w = (u32)o[6] | ((u32)o[7] << 16);
            wf2[kt] = *(bf16x8*)&pk;
        }
        int hs = (l < 3) ? l : 0;
#pragma unroll
        for (int g = 0; g < 4; ++g) {
#pragma unroll
            for (int q = 0; q < 3; ++q) wh[g][q] = w_hh2[(g * 3 + hs) * 3 + q];
            b2l[g] = b_ih2[g * 3 + hs] + b_hh2[g * 3 + hs];
        }
#pragma unroll
        for (int r = 0; r < 4; ++r) { h2p[r] = 0.f; c2[r] = 0.f; }
    }

    float creg[4] = {0.f, 0.f, 0.f, 0.f};

    auto L2EW = [&](int tout) {
        int hs = (l < 3) ? l : 0;
#pragma unroll
        for (int r = 0; r < 4; ++r) {
            float pi = __shfl(acc2[r], hs);
            float pf = __shfl(acc2[r], 3 + hs);
            float pg = __shfl(acc2[r], 6 + hs);
            float po = __shfl(acc2[r], 9 + hs);
            float hq0 = __shfl(h2p[r], 0);
            float hq1 = __shfl(h2p[r], 1);
            float hq2 = __shfl(h2p[r], 2);
            pi += b2l[0] + wh[0][0] * hq0 + wh[0][1] * hq1 + wh[0][2] * hq2;
            pf += b2l[1] + wh[1][0] * hq0 + wh[1][1] * hq1 + wh[1][2] * hq2;
            pg += b2l[2] + wh[2][0] * hq0 + wh[2][1] * hq1 + wh[2][2] * hq2;
            po += b2l[3] + wh[3][0] * hq0 + wh[3][1] * hq1 + wh[3][2] * hq2;
            float gi = sig2(pi), gf = sig2(pf), gg = tanh2(pg), go = sig2(po);
            c2[r] = gf * c2[r] + gi * gg;
            h2p[r] = go * tanh2(c2[r]);
            if (l < 3) out[(size_t)tout * 768 + (mw * 4 + r) * 3 + l] = h2p[r];
        }
    };

    // staging: every wave its own batch row, 1600 B/step (64 + 36 lanes x 16B)
    const char* sp = (const char*)xg + (size_t)mw * XG_WG_BYTES + (size_t)wv * 1600;
    {
        char* d = (char*)xgs + wv * 1600; // buf 0 (t=0)
        G2L16(sp + (size_t)l * 16, d);
        if (l < 36) G2L16(sp + 1024 + (size_t)l * 16, d + 1024);
        sp += XG_T_BYTES;
        asm volatile("s_waitcnt vmcnt(0)" ::: "memory");
    }
    __builtin_amdgcn_s_barrier();

    for (int t = 0; t < T_STEPS; ++t) {
        bf16x8 ha0 = LDHB(0), ha1 = LDHB(1), ha2 = LDHB(2);
        bf16x8 wb0[NL ? NL : 1], wb1[NL ? NL : 1];
#pragma unroll
        for (int j = 0; j < NL; ++j) wb0[j] = LDSW(j, 0);

        { // stage xg(t+1); stays in flight across the barrier
            char* d = (char*)xgs + ((t + 1) & 1) * XG_WG_BYTES + wv * 1600;
            G2L16(sp + (size_t)l * 16, d);
            if (l < 36) G2L16(sp + 1024 + (size_t)l * 16, d + 1024);
            sp += XG_T_BYTES;
        }
        if constexpr (L2O) {
            if (t >= 2) L2EW(t - 2); // consumes prev-iteration acc2
        }

        f32x4 acc[8], accL[NL ? NL : 1];
        // kt = 0
#pragma unroll
        for (int nt = 0; nt < 8; ++nt)
            acc[nt] = __builtin_amdgcn_mfma_f32_16x16x32_bf16(ha0, wf[nt][0], fz, 0, 0, 0);
#pragma unroll
        for (int j = 0; j < NL; ++j) accL[j] = __builtin_amdgcn_mfma_f32_16x16x32_bf16(ha0, wb0[j], fz, 0, 0, 0);
#pragma unroll
        for (int j = 0; j < NL; ++j) wb1[j] = LDSW(j, 1);
        if constexpr (L2O) acc2 = __builtin_amdgcn_mfma_f32_16x16x32_bf16(ha0, wf2[0], fz, 0, 0, 0);
        ha0 = LDHB(3);
        // kt = 1
#pragma unroll
        for (int nt = 0; nt < 8; ++nt)
            acc[nt] = __builtin_amdgcn_mfma_f32_16x16x32_bf16(ha1, wf[nt][1], acc[nt], 0, 0, 0);
#pragma unroll
        for (int j = 0; j < NL; ++j) accL[j] = __builtin_amdgcn_mfma_f32_16x16x32_bf16(ha1, wb1[j], accL[j], 0, 0, 0);
#pragma unroll
        for (int j = 0; j < NL; ++j) wb0[j] = LDSW(j, 2);
        if constexpr (L2O) acc2 = __builtin_amdgcn_mfma_f32_16x16x32_bf16(ha1, wf2[1], acc2, 0, 0, 0);
        ha1 = LDHB(4);
        // kt = 2
#pragma unroll
        for (int nt = 0; nt < 8; ++nt)
            acc[nt] = __builtin_amdgcn_mfma_f32_16x16x32_bf16(ha2, wf[nt][2], acc[nt], 0, 0, 0);
#pragma unroll
        for (int j = 0; j < NL; ++j) accL[j] = __builtin_amdgcn_mfma_f32_16x16x32_bf16(ha2, wb0[j], accL[j], 0, 0, 0);
#pragma unroll
        for (int j = 0; j < NL; ++j) wb1[j] = LDSW(j, 3);
        if constexpr (L2O) acc2 = __builtin_amdgcn_mfma_f32_16x16x32_bf16(ha2, wf2[2], acc2, 0, 0, 0);
        ha2 = LDHB(5);
        // kt = 3
#pragma unroll
        for (int nt = 0; nt < 8; ++nt)
            acc[nt] = __builtin_amdgcn_mfma_f32_16x16x32_bf16(ha0, wf[nt][3], acc[nt], 0, 0, 0);
#pragma unroll
        for (int j = 0; j < NL; ++j) accL[j] = __builtin_amdgcn_mfma_f32_16x16x32_bf16(ha0, wb1[j], accL[j], 0, 0, 0);
#pragma unroll
        for (int j = 0; j < NL; ++j) wb0[j] = LDSW(j, 4);
        if constexpr (L2O) acc2 = __builtin_amdgcn_mfma_f32_16x16x32_bf16(ha0, wf2[3], acc2, 0, 0, 0);
        ha0 = LDHB(6);
        // kt = 4
#pragma unroll
        for (int nt = 0; nt < 8; ++nt)
            acc[nt] = __builtin_amdgcn_mfma_f32_16x16x32_bf16(ha1, wf[nt][4], acc[nt], 0, 0, 0);
#pragma unroll
        for (int j = 0; j < NL; ++j) accL[j] = __builtin_amdgcn_mfma_f32_16x16x32_bf16(ha1, wb0[j], accL[j], 0, 0, 0);
#pragma unroll
        for (int j = 0; j < NL; ++j) wb1[j] = LDSW(j, 5);
        if constexpr (L2O) acc2 = __builtin_amdgcn_mfma_f32_16x16x32_bf16(ha1, wf2[4], acc2, 0, 0, 0);
        // kt = 5
#pragma unroll
        for (int nt = 0; nt < 8; ++nt)
            acc[nt] = __builtin_amdgcn_mfma_f32_16x16x32_bf16(ha2, wf[nt][5], acc[nt], 0, 0, 0);
#pragma unroll
        for (int j = 0; j < NL; ++j) accL[j] = __builtin_amdgcn_mfma_f32_16x16x32_bf16(ha2, wb1[j], accL[j], 0, 0, 0);
#pragma unroll
        for (int j = 0; j < NL; ++j) wb0[j] = LDSW(j, 6);
        if constexpr (L2O) acc2 = __builtin_amdgcn_mfma_f32_16x16x32_bf16(ha2, wf2[5], acc2, 0, 0, 0);
        // kt = 6
#pragma unroll
        for (int nt = 0; nt < 8; ++nt)
            acc[nt] = __builtin_amdgcn_mfma_f32_16x16x32_bf16(ha0, wf[nt][6], acc[nt], 0, 0, 0);
#pragma unroll
        for (int j = 0; j < NL; ++j) accL[j] = __builtin_amdgcn_mfma_f32_16x16x32_bf16(ha0, wb0[j], accL[j], 0, 0, 0);
        if constexpr (L2O) acc2 = __builtin_amdgcn_mfma_f32_16x16x32_bf16(ha0, wf2[6], acc2, 0, 0, 0);

        // gate stores: lanes<16, stride-1 cols, conflict-free
        if (l < 16) {
#pragma unroll
            for (int nt = 0; nt < 8; ++nt) {
                int col = (tile0 + nt) * 16 + l;
#pragma unroll
                for (int r = 0; r < 4; ++r) gbuf[r * G1 + col] = acc[nt][r];
            }
#pragma unroll
            for (int j = 0; j < NL; ++j) {
                int col = (32 + slot0 + j) * 16 + l;
#pragma unroll
                for (int r = 0; r < 4; ++r) gbuf[r * G1 + col] = accL[j][r];
            }
        }

        asm volatile("s_waitcnt vmcnt(2)" ::: "memory"); // xg(t) ready; t+1 in flight
        asm volatile("s_waitcnt lgkmcnt(0)" ::: "memory");
        __builtin_amdgcn_s_barrier(); // b1

        // layer-1 elementwise: wave = batch row wv, j = r*64 + l (r4-verified)
        {
            const float* gb = gbuf + wv * G1;
            const u16* xr = xgs + (t & 1) * 3200 + wv * XGW;
#pragma unroll
            for (int r = 0; r < 4; ++r) {
                int j = r * 64 + l;
                if (r < 3 || l < 8) {
                    float pi = gb[j] + bfu2f(xr[j]);
                    float pf = gb[H1 + j] + bfu2f(xr[H1 + j]);
                    float pg = gb[2 * H1 + j] + bfu2f(xr[2 * H1 + j]);
                    float po = gb[3 * H1 + j] + bfu2f(xr[3 * H1 + j]);
                    float gi = sig2(pi), gf = sig2(pf), gg = tanh2(pg), go = sig2(po);
                    float c = gf * creg[r] + gi * gg;
                    creg[r] = c;
                    float h = go * tanh2(c);
                    *(u16*)((char*)hbuf + ((wv * 448 + j * 2) ^ (wv << 4))) = f2bf(h);
                }
            }
        }

        asm volatile("s_waitcnt lgkmcnt(0)" ::: "memory");
        __builtin_amdgcn_s_barrier(); // b2
    }

    asm volatile("s_waitcnt vmcnt(0)" ::: "memory"); // drain dangling t=512 stage

    // epilogue (wave 3): layer-2 for steps 510 and 511 (r4-verified)
    if constexpr (L2O) {
        L2EW(510);
        bf16x8 he = LDHB(0);
        acc2 = __builtin_amdgcn_mfma_f32_16x16x32_bf16(he, wf2[0], fz, 0, 0, 0);
#pragma unroll
        for (int kt = 1; kt < 7; ++kt) {
            he = LDHB(kt);
            acc2 = __builtin_amdgcn_mfma_f32_16x16x32_bf16(he, wf2[kt], acc2, 0, 0, 0);
        }
        L2EW(511);
    }
}

__global__ __launch_bounds__(256, 1)
void lstm_main(const u16* __restrict__ xg,
               const u16* __restrict__ whhf,
               const float* __restrict__ w_ih2,
               const float* __restrict__ w_hh2,
               const float* __restrict__ b_ih2,
               const float* __restrict__ b_hh2,
               float* __restrict__ out) {
    // single mega-array: exact 156,448 B (no inter-array padding surprises)
    __shared__ __align__(16) char smem[156448];
    u16* wlds = (u16*)smem;                      // 18 tiles x 7168 = 129,024
    u16* hbuf = (u16*)(smem + 129024);           // 4 x 448 + 16-B zero slot = 1,824
    u16* xgs = (u16*)(smem + 130848);            // 2 x 6400 = 12,800
    float* gbuf = (float*)(smem + 143648);       // 4 x 800 x 4 = 12,800

    int tid = threadIdx.x, mw = blockIdx.x;
    int l = tid & 63, wv = tid >> 6;

    for (int i = tid; i < 912; i += 256) hbuf[i] = 0; // rows 0-3 + zero slot
    // copy tiles 32..49 B-fragments into LDS (contiguous in whhf)
    {
        const uint4* src = (const uint4*)(whhf + (size_t)(32 * 7) * 512);
        uint4* dst = (uint4*)wlds;
        for (int i = tid; i < 8064; i += 256) dst[i] = src[i];
    }
    __syncthreads();

    // reg tiles: wave w -> [w*8, w*8+8); LDS tiles 32-49: w0:5, w1:5, w2:5, w3:3 (+L2)
    if (wv == 0)
        lstm_body<5, false>(0, 0, 0, l, mw, xg, whhf, w_ih2, w_hh2, b_ih2, b_hh2, out, hbuf, gbuf, xgs, wlds);
    else if (wv == 1)
        lstm_body<5, false>(8, 5, 1, l, mw, xg, whhf, w_ih2, w_hh2, b_ih2, b_hh2, out, hbuf, gbuf, xgs, wlds);
    else if (wv == 2)
        lstm_body<5, false>(16, 10, 2, l, mw, xg, whhf, w_ih2, w_hh2, b_ih2, b_hh2, out, hbuf, gbuf, xgs, wlds);
    else
        lstm_body<3, true>(24, 15, 3, l, mw, xg, whhf, w_ih2, w_hh2, b_ih2, b_hh2, out, hbuf, gbuf, xgs, wlds);
}

extern "C" void kernel_launch(void* const* d_in, const int* in_sizes, int n_in,
                              void* d_out, int out_size, void* d_ws, size_t ws_size,
                              hipStream_t stream) {
    const float* X = (const float*)d_in[0];
    const float* w_ih1 = (const float*)d_in[1];
    const float* w_hh1 = (const float*)d_in[2];
    const float* b_ih1 = (const float*)d_in[3];
    const float* b_hh1 = (const float*)d_in[4];
    const float* w_ih2 = (const float*)d_in[5];
    const float* w_hh2 = (const float*)d_in[6];
    const float* b_ih2 = (const float*)d_in[7];
    const float* b_hh2 = (const float*)d_in[8];
    float* out = (float*)d_out;

    char* ws = (char*)d_ws;
    size_t off = 0;
    u16* xg = (u16*)(ws + off);
    off += (size_t)512 * 256 * XGW * 2; // 209,715,200 B (800-col natural layout)
    u16* whhf = (u16*)(ws + off);
    off += (size_t)22400 * 8 * 2; // 358,400 B (also absorbs t=512 stage overread)
    u16* wihf = (u16*)(ws + off);
    off += (size_t)13312 * 8 * 2; // 212,992 B
    float* b1p = (float*)(ws + off);
    off += G1P * 4;
    if (ws_size < off) return; // insufficient workspace -> visible failure

    repack_k<<<140, 256, 0, stream>>>(w_ih1, w_hh1, b_ih1, b_hh1, wihf, whhf, b1p);
    xg_gemm<<<2048, 256, 0, stream>>>(X, wihf, b1p, xg);
    lstm_main<<<64, 256, 0, stream>>>(xg, whhf, w_ih2, w_hh2, b_ih2, b_hh2, out);
}

// Round 13
// 946.941 us; speedup vs baseline: 1.7664x; 1.7664x over previous
//
#include <hip/hip_runtime.h>

typedef unsigned short u16;
typedef unsigned int u32;
typedef __attribute__((ext_vector_type(8))) short bf16x8;
typedef __attribute__((ext_vector_type(4))) float f32x4;

#define T_STEPS 512
#define FEAT 128
#define H1 200
#define G1P 832             // 4 gates x 208 padded cols
#define XG_T_BYTES 425984   // 256 * 832 * 2
#define XG_ROW_BYTES 1664   // 832 * 2

// async global->LDS, 16B/lane; LDS dest wave-uniform base (+lane*16 in HW)
#define G2L16(g, lp) __builtin_amdgcn_global_load_lds( \
    (const __attribute__((address_space(1))) void*)(g), \
    (__attribute__((address_space(3))) void*)(lp), 16, 0, 0)

__device__ __forceinline__ u16 f2bf(float x) {
    u32 u = __float_as_uint(x);
    u = (u + 0x7fffu + ((u >> 16) & 1u)) >> 16;
    return (u16)u;
}
__device__ __forceinline__ float bfu2f(u32 u) { return __uint_as_float(u << 16); }

__device__ __forceinline__ float sig2(float x) {
    return __builtin_amdgcn_rcpf(1.f + __builtin_amdgcn_exp2f(-1.442695041f * x));
}
__device__ __forceinline__ float tanh2(float x) {
    return 1.f - 2.f * __builtin_amdgcn_rcpf(1.f + __builtin_amdgcn_exp2f(2.885390082f * x));
}

// ---------------------------------------------------------------------------
// Kernel 1: repack to bf16 B-fragment order in PADDED column space (r11-verified).
// col' in [0,832): gate g = col'/208, j = col'%208; raw row = g*200+j (0 for j>=200).
// whhf: 52 tiles [tile*7+kt][lane][8]; tile t: gate t/13, hidden cols (t%13)*16+.
// ---------------------------------------------------------------------------
__global__ void repack_k(const float* __restrict__ wih1, const float* __restrict__ whh1,
                         const float* __restrict__ bih1, const float* __restrict__ bhh1,
                         u16* __restrict__ wihf, u16* __restrict__ whhf, float* __restrict__ b1p) {
    int id = blockIdx.x * 256 + threadIdx.x;
    if (id < G1P) {
        int g = id / 208, j = id - g * 208;
        b1p[id] = (j < H1) ? (bih1[g * H1 + j] + bhh1[g * H1 + j]) : 0.f;
    }
    if (id < 23296) { // 52*7*64 lane-slots for whh
        int l = id & 63, fi = id >> 6;
        int kt = fi % 7, tile = fi / 7;
        int g = tile / 13, jt = tile - g * 13;
        int j = jt * 16 + (l & 15);
        int kb = kt * 32 + (l >> 4) * 8;
        u16 o[8];
#pragma unroll
        for (int jj = 0; jj < 8; ++jj) {
            int k = kb + jj;
            float v = (j < H1 && k < H1) ? whh1[(g * H1 + j) * H1 + k] : 0.f;
            o[jj] = f2bf(v);
        }
        uint4 pk;
        pk.x = (u32)o[0] | ((u32)o[1] << 16);
        pk.y = (u32)o[2] | ((u32)o[3] << 16);
        pk.z = (u32)o[4] | ((u32)o[5] << 16);
        pk.w = (u32)o[6] | ((u32)o[7] << 16);
        *(uint4*)(whhf + (size_t)id * 8) = pk;
    }
    int id2 = id - 23296;
    if (id2 >= 0 && id2 < 13312) { // 52*4*64 lane-slots for wih
        int l = id2 & 63, fi = id2 >> 6;
        int kt = fi & 3, tile = fi >> 2;
        int g = tile / 13, jt = tile - g * 13;
        int j = jt * 16 + (l & 15);
        int kb = kt * 32 + (l >> 4) * 8;
        u16 o[8];
#pragma unroll
        for (int jj = 0; jj < 8; ++jj) {
            int k = kb + jj;
            float v = (j < H1) ? wih1[(g * H1 + j) * FEAT + k] : 0.f;
            o[jj] = f2bf(v);
        }
        uint4 pk;
        pk.x = (u32)o[0] | ((u32)o[1] << 16);
        pk.y = (u32)o[2] | ((u32)o[3] << 16);
        pk.z = (u32)o[4] | ((u32)o[5] << 16);
        pk.w = (u32)o[6] | ((u32)o[7] << 16);
        *(uint4*)(wihf + (size_t)id2 * 8) = pk;
    }
}

// ---------------------------------------------------------------------------
// Kernel 2: xg = X @ W_ih1^T + bias, bf16, natural layout xg[t][b][col' 0..831]
// in padded column space (r11-verified verbatim).
// ---------------------------------------------------------------------------
__global__ __launch_bounds__(256, 1) void xg_gemm(const float* __restrict__ X,
                                                  const u16* __restrict__ wihf,
                                                  const float* __restrict__ b1p,
                                                  u16* __restrict__ xg) {
    __shared__ u16 xs[64 * 128];
    int tid = threadIdx.x, wg = blockIdx.x;
    int l = tid & 63, wv = tid >> 6;
    int arow = l & 15, khi = l >> 4;

    const float4* Xv = (const float4*)(X + (size_t)wg * 64 * 128);
#pragma unroll
    for (int i = 0; i < 8; ++i) {
        int idx = tid + i * 256;
        float4 v = Xv[idx];
        int row = idx >> 5;
        int col = (idx & 31) * 4;
        uint2 pk;
        pk.x = (u32)f2bf(v.x) | ((u32)f2bf(v.y) << 16);
        pk.y = (u32)f2bf(v.z) | ((u32)f2bf(v.w) << 16);
        int byteo = (row * 256 + col * 2) ^ ((row & 7) << 4);
        *(uint2*)((char*)xs + byteo) = pk;
    }
    __syncthreads();

    f32x4 acc[4][13];
#pragma unroll
    for (int mt = 0; mt < 4; ++mt)
#pragma unroll
        for (int nt = 0; nt < 13; ++nt) acc[mt][nt] = (f32x4){0.f, 0.f, 0.f, 0.f};

#pragma unroll
    for (int kt = 0; kt < 4; ++kt) {
        bf16x8 wfr[13];
#pragma unroll
        for (int nt = 0; nt < 13; ++nt) {
            int ntg = wv * 13 + nt;
            wfr[nt] = *(const bf16x8*)(wihf + ((size_t)(ntg * 4 + kt) * 64 + l) * 8);
        }
#pragma unroll
        for (int mt = 0; mt < 4; ++mt) {
            int row = mt * 16 + arow;
            int byteo = (row * 256 + kt * 64 + khi * 16) ^ ((row & 7) << 4);
            bf16x8 a = *(const bf16x8*)((const char*)xs + byteo);
#pragma unroll
            for (int nt = 0; nt < 13; ++nt)
                acc[mt][nt] = __builtin_amdgcn_mfma_f32_16x16x32_bf16(a, wfr[nt], acc[mt][nt], 0, 0, 0);
        }
    }

    int t = wg >> 2;
#pragma unroll
    for (int nt = 0; nt < 13; ++nt) {
        int ntg = wv * 13 + nt;
        int colg = ntg * 16 + arow;
        float bias = b1p[colg];
#pragma unroll
        for (int mt = 0; mt < 4; ++mt) {
#pragma unroll
            for (int r = 0; r < 4; ++r) {
                int bg = (wg & 3) * 64 + mt * 16 + khi * 4 + r;
                xg[((size_t)t * 256 + bg) * G1P + colg] = f2bf(acc[mt][nt][r] + bias);
            }
        }
    }
}

// ---------------------------------------------------------------------------
// Kernel 3: persistent fused 2-layer LSTM. 256 WGs x 512 threads, ONE batch
// row per WG (all 256 CUs; LDS padded to force 1 WG/CU). ALL 52 weight tiles
// in registers/AGPRs (zero LDS weight traffic). Wave owns complete gate-
// column groups {g, g+13, g+26, g+39} -> EW fully in-register (no gbuf).
// h: row-0 only, double-buffered 224-col LDS, broadcast reads. 1 barrier/step.
// ---------------------------------------------------------------------------
#define LDHB(KT) (*(const bf16x8*)(hbr + (KT) * 64 + khi * 16))

template<int NG, int MODE>  // MODE: 0 plain, 1 stager (waves 5,6), 2 layer-2 owner
__device__ __forceinline__ void lstm_body(
    int g0, int wv, int l, int mw,
    const u16* __restrict__ xg, const u16* __restrict__ whhf,
    const float* __restrict__ w_ih2, const float* __restrict__ w_hh2,
    const float* __restrict__ b_ih2, const float* __restrict__ b_hh2,
    float* __restrict__ out, u16* hbuf, u16* xgs)
{
    const int arow = l & 15, khi = l >> 4;
    const f32x4 fz = {0.f, 0.f, 0.f, 0.f};

    // all weight tiles for this wave's groups: {g0+gg, +13, +26, +39}
    bf16x8 wf[NG][4][7];
#pragma unroll
    for (int gg = 0; gg < NG; ++gg)
#pragma unroll
        for (int gt = 0; gt < 4; ++gt) {
            int tile = (g0 + gg) + 13 * gt;
#pragma unroll
            for (int kt = 0; kt < 7; ++kt)
                wf[gg][gt][kt] = *(const bf16x8*)(whhf + ((size_t)(tile * 7 + kt) * 64 + l) * 8);
        }

    // layer-2 state (wave 7 only)
    bf16x8 wf2[7];
    float wh[4][3], b2l[4];
    float h2p = 0.f, c2 = 0.f;
    f32x4 acc2 = fz;
    if constexpr (MODE == 2) {
#pragma unroll
        for (int kt = 0; kt < 7; ++kt) {
            u16 o[8];
#pragma unroll
            for (int jj = 0; jj < 8; ++jj) {
                int k = kt * 32 + khi * 8 + jj;
                o[jj] = (arow < 12 && k < H1) ? f2bf(w_ih2[arow * H1 + k]) : (u16)0;
            }
            uint4 pk;
            pk.x = (u32)o[0] | ((u32)o[1] << 16);
            pk.y = (u32)o[2] | ((u32)o[3] << 16);
            pk.z = (u32)o[4] | ((u32)o[5] << 16);
            pk.w = (u32)o[6] | ((u32)o[7] << 16);
            wf2[kt] = *(bf16x8*)&pk;
        }
        int hs = (l < 3) ? l : 0;
#pragma unroll
        for (int g = 0; g < 4; ++g) {
#pragma unroll
            for (int q = 0; q < 3; ++q) wh[g][q] = w_hh2[(g * 3 + hs) * 3 + q];
            b2l[g] = b_ih2[g * 3 + hs] + b_hh2[g * 3 + hs];
        }
    }

    float creg[NG];
#pragma unroll
    for (int gg = 0; gg < NG; ++gg) creg[gg] = 0.f;

    // layer-2 elementwise, batch row 0 only (acc2 row0 = lanes 0-15, reg 0)
    auto L2EW = [&](int tout) {
        int hs = (l < 3) ? l : 0;
        float pi = __shfl(acc2[0], hs);
        float pf = __shfl(acc2[0], 3 + hs);
        float pg = __shfl(acc2[0], 6 + hs);
        float po = __shfl(acc2[0], 9 + hs);
        float hq0 = __shfl(h2p, 0);
        float hq1 = __shfl(h2p, 1);
        float hq2 = __shfl(h2p, 2);
        pi += b2l[0] + wh[0][0] * hq0 + wh[0][1] * hq1 + wh[0][2] * hq2;
        pf += b2l[1] + wh[1][0] * hq0 + wh[1][1] * hq1 + wh[1][2] * hq2;
        pg += b2l[2] + wh[2][0] * hq0 + wh[2][1] * hq1 + wh[2][2] * hq2;
        po += b2l[3] + wh[3][0] * hq0 + wh[3][1] * hq1 + wh[3][2] * hq2;
        float gi = sig2(pi), gf = sig2(pf), gg2 = tanh2(pg), go = sig2(po);
        c2 = gf * c2 + gi * gg2;
        h2p = go * tanh2(c2);
        if (l < 3) out[(size_t)tout * 768 + mw * 3 + l] = h2p;
    };

    // staging: waves 5,6 each cover half the 1664-B row (52 lanes x 16 B)
    const char* sp = (const char*)xg + (size_t)mw * XG_ROW_BYTES + (size_t)(wv - 5) * 832;
    if constexpr (MODE == 1) {
        char* d = (char*)xgs + (wv - 5) * 832;  // buf 0 (t=0)
        if (l < 52) G2L16(sp + (size_t)l * 16, d);
        sp += XG_T_BYTES;
        asm volatile("s_waitcnt vmcnt(0)" ::: "memory");
    }
    __syncthreads();

    for (int t = 0; t < T_STEPS; ++t) {
        const char* hbr = (const char*)(hbuf + (t & 1) * 224);
        u16* hbw = hbuf + ((t + 1) & 1) * 224;
        const u16* xr = xgs + (t & 1) * 832;

        // h fragments (row-0 broadcast: 4 distinct 16B addrs, conflict-free)
        bf16x8 ha[7];
#pragma unroll
        for (int kt = 0; kt < 7; ++kt) ha[kt] = LDHB(kt);

        if constexpr (MODE == 1) { // stage xg(t+1); stays in flight across barrier
            char* d = (char*)xgs + ((t + 1) & 1) * 1664 + (wv - 5) * 832;
            if (l < 52) G2L16(sp + (size_t)l * 16, d);
            sp += XG_T_BYTES;
        }
        if constexpr (MODE == 2) {
            if (t >= 2) L2EW(t - 2); // consumes prev-iteration acc2
        }

        f32x4 acc[NG][4];
#pragma unroll
        for (int kt = 0; kt < 7; ++kt) {
#pragma unroll
            for (int gg = 0; gg < NG; ++gg)
#pragma unroll
                for (int gt = 0; gt < 4; ++gt)
                    acc[gg][gt] = __builtin_amdgcn_mfma_f32_16x16x32_bf16(
                        ha[kt], wf[gg][gt][kt], kt == 0 ? fz : acc[gg][gt], 0, 0, 0);
            if constexpr (MODE == 2)
                acc2 = __builtin_amdgcn_mfma_f32_16x16x32_bf16(ha[kt], wf2[kt], kt == 0 ? fz : acc2, 0, 0, 0);
        }

        // in-register elementwise: lanes 0-15 hold row 0 of every gate tile
        if (l < 16) {
#pragma unroll
            for (int gg = 0; gg < NG; ++gg) {
                int j = (g0 + gg) * 16 + l; // hidden col in padded [0,208)
                float pi = acc[gg][0][0] + bfu2f(xr[j]);
                float pf = acc[gg][1][0] + bfu2f(xr[208 + j]);
                float pg = acc[gg][2][0] + bfu2f(xr[416 + j]);
                float po = acc[gg][3][0] + bfu2f(xr[624 + j]);
                float gi = sig2(pi), gf = sig2(pf), gv = tanh2(pg), go = sig2(po);
                float c = gf * creg[gg] + gi * gv;
                creg[gg] = c;
                hbw[j] = f2bf(go * tanh2(c)); // pad cols j>=200 harmless (K-pad weights = 0)
            }
        }

        if constexpr (MODE == 1) asm volatile("s_waitcnt vmcnt(1)" ::: "memory"); // xg(t+1) may stay in flight
        asm volatile("s_waitcnt lgkmcnt(0)" ::: "memory");
        __builtin_amdgcn_s_barrier(); // single barrier per step
    }

    asm volatile("s_waitcnt vmcnt(0)" ::: "memory"); // drain dangling t=512 stage

    // epilogue (wave 7): layer-2 for steps 510 and 511
    if constexpr (MODE == 2) {
        L2EW(510);
        const char* hbr = (const char*)(hbuf + (T_STEPS & 1) * 224); // h(511)
        bf16x8 he = LDHB(0);
        acc2 = __builtin_amdgcn_mfma_f32_16x16x32_bf16(he, wf2[0], fz, 0, 0, 0);
#pragma unroll
        for (int kt = 1; kt < 7; ++kt) {
            he = LDHB(kt);
            acc2 = __builtin_amdgcn_mfma_f32_16x16x32_bf16(he, wf2[kt], acc2, 0, 0, 0);
        }
        L2EW(511);
    }
}

__global__ __launch_bounds__(512, 2)
void lstm_main(const u16* __restrict__ xg,
               const u16* __restrict__ whhf,
               const float* __restrict__ w_ih2,
               const float* __restrict__ w_hh2,
               const float* __restrict__ b_ih2,
               const float* __restrict__ b_hh2,
               float* __restrict__ out) {
    __shared__ __align__(16) u16 hbuf[2 * 224];   //   896 B, dbuf'd h (row 0 only)
    __shared__ __align__(16) u16 xgs[2 * 832];    //  3328 B, staged xg (dbuf)
    __shared__ char ldspad[84000];                // forces 1 WG/CU (no 2-WG packing)

    int tid = threadIdx.x, mw = blockIdx.x;
    int l = tid & 63, wv = tid >> 6;

    for (int i = tid; i < 448; i += 512) hbuf[i] = 0;
    ((volatile char*)ldspad)[tid] = 0; // keep pad alive

    // group map: w0-w4 -> 2 groups each (0-9); w5,w6 -> 1 group + staging; w7 -> group 12 + layer-2
    if (wv < 5)
        lstm_body<2, 0>(wv * 2, wv, l, mw, xg, whhf, w_ih2, w_hh2, b_ih2, b_hh2, out, hbuf, xgs);
    else if (wv < 7)
        lstm_body<1, 1>(10 + (wv - 5), wv, l, mw, xg, whhf, w_ih2, w_hh2, b_ih2, b_hh2, out, hbuf, xgs);
    else
        lstm_body<1, 2>(12, wv, l, mw, xg, whhf, w_ih2, w_hh2, b_ih2, b_hh2, out, hbuf, xgs);
}

extern "C" void kernel_launch(void* const* d_in, const int* in_sizes, int n_in,
                              void* d_out, int out_size, void* d_ws, size_t ws_size,
                              hipStream_t stream) {
    const float* X = (const float*)d_in[0];
    const float* w_ih1 = (const float*)d_in[1];
    const float* w_hh1 = (const float*)d_in[2];
    const float* b_ih1 = (const float*)d_in[3];
    const float* b_hh1 = (const float*)d_in[4];
    const float* w_ih2 = (const float*)d_in[5];
    const float* w_hh2 = (const float*)d_in[6];
    const float* b_ih2 = (const float*)d_in[7];
    const float* b_hh2 = (const float*)d_in[8];
    float* out = (float*)d_out;

    char* ws = (char*)d_ws;
    size_t off = 0;
    u16* xg = (u16*)(ws + off);
    off += (size_t)512 * 256 * G1P * 2; // 218,103,808 B
    u16* whhf = (u16*)(ws + off);
    off += (size_t)23296 * 8 * 2; // 372,736 B (also absorbs t=512 stage overread)
    u16* wihf = (u16*)(ws + off);
    off += (size_t)13312 * 8 * 2; // 212,992 B
    float* b1p = (float*)(ws + off);
    off += G1P * 4;
    if (ws_size < off) return; // insufficient workspace -> visible failure

    repack_k<<<143, 256, 0, stream>>>(w_ih1, w_hh1, b_ih1, b_hh1, wihf, whhf, b1p);
    xg_gemm<<<2048, 256, 0, stream>>>(X, wihf, b1p, xg);
    lstm_main<<<256, 512, 0, stream>>>(xg, whhf, w_ih2, w_hh2, b_ih2, b_hh2, out);
}